// Round 1
// baseline (66.044 us; speedup 1.0000x reference)
//
#include <hip/hip_runtime.h>
#include <math.h>

// TensoIR physical rendering: N points x L lights -> 4 (N,3) outputs
// (rgb, wo_indir, wo_vis, indir), each linear->sRGB'd after the light sum.
//
// Layout decision: one WAVE per point n (64 lanes split the L=512 lights),
// 4 waves (4 points) per 256-thread block. Light table (normalized dir,
// area weight, env rgb) staged once per block into LDS (16 KB).
// visibility reads: 4 B/lane stride-1 coalesced. indirect reads: 12 B/lane
// contiguous. Memory-bound: ~258 MB read -> ~41 us floor at 6.3 TB/s.

#define PI_F     3.14159265358979323846f
#define FOURPI_F (4.0f * PI_F)
#define MAXL     512

// Fast HW transcendentals (v_rcp/v_rsq/v_exp/v_log ~1ulp rel err; output
// threshold is 9.3e-2 absolute, so plenty of margin).
__device__ __forceinline__ float fast_rcp(float x)  { float r; asm("v_rcp_f32 %0, %1" : "=v"(r) : "v"(x)); return r; }
__device__ __forceinline__ float fast_exp2(float x) { float r; asm("v_exp_f32 %0, %1" : "=v"(r) : "v"(x)); return r; }
__device__ __forceinline__ float fast_log2(float x) { float r; asm("v_log_f32 %0, %1" : "=v"(r) : "v"(x)); return r; }

__device__ __forceinline__ float lin2srgb(float x) {
  float lin = 12.92f * x;
  float xe  = fmaxf(x, 1e-8f);
  float e   = 1.055f * fast_exp2(fast_log2(xe) * (1.0f / 2.4f)) - 0.055f;
  return (x <= 0.0031308f) ? lin : e;
}

__device__ __forceinline__ float clamp01(float x) { return fminf(fmaxf(x, 0.0f), 1.0f); }

__global__ void __launch_bounds__(256)
tensoir_render(const float* __restrict__ viewdirs,  // (N,3)
               const float* __restrict__ albedo,    // (N,3)
               const float* __restrict__ roughness, // (N,1)
               const float* __restrict__ fresnel,   // (N,3)
               const float* __restrict__ normal,    // (N,3)
               const float* __restrict__ light_dirs,// (L,3)
               const float* __restrict__ law,       // (L,)
               const float* __restrict__ env_rgbs,  // (L,3)
               const float* __restrict__ visibility,// (N,L,1)
               const float* __restrict__ indirect,  // (N,L,3)
               float* __restrict__ out,             // 4*N*3
               int N, int L) {
  __shared__ float4 s_ld[MAXL];   // normalized light dir xyz, area weight
  __shared__ float4 s_env[MAXL];  // env rgb, pad

  const int tid = threadIdx.x;

  // Stage light table (per block). L=512, 256 threads -> 2 lights each.
  for (int l = tid; l < L && l < MAXL; l += 256) {
    float lx = light_dirs[3 * l + 0];
    float ly = light_dirs[3 * l + 1];
    float lz = light_dirs[3 * l + 2];
    float len = sqrtf(lx * lx + ly * ly + lz * lz);
    float inv = fast_rcp(fmaxf(len, 1e-6f));
    s_ld[l]  = make_float4(lx * inv, ly * inv, lz * inv, law[l]);
    s_env[l] = make_float4(env_rgbs[3 * l + 0], env_rgbs[3 * l + 1],
                           env_rgbs[3 * l + 2], 0.0f);
  }
  __syncthreads();

  const int lane = tid & 63;
  const int n = blockIdx.x * 4 + (tid >> 6);
  if (n >= N) return;

  // ---- per-point (wave-uniform) setup, computed redundantly per lane ----
  float vx = -viewdirs[3 * n + 0], vy = -viewdirs[3 * n + 1], vz = -viewdirs[3 * n + 2];
  {
    float len = sqrtf(vx * vx + vy * vy + vz * vz);
    float inv = fast_rcp(fmaxf(len, 1e-6f));
    vx *= inv; vy *= inv; vz *= inv;
  }
  float nx = normal[3 * n + 0], ny = normal[3 * n + 1], nz = normal[3 * n + 2];
  {
    float len = sqrtf(nx * nx + ny * ny + nz * nz);
    float inv = fast_rcp(fmaxf(len, 1e-6f));
    nx *= inv; ny *= inv; nz *= inv;
  }
  float rough = roughness[n];
  rough = clamp01(rough * 0.9f + 0.09f);
  const float alpha  = rough * rough;
  const float alpha2 = alpha * alpha;
  const float kk     = (alpha + 2.0f * rough + 1.0f) * 0.125f;
  const float onemk  = 1.0f - kk;

  const float fr = fresnel[3 * n + 0], fg = fresnel[3 * n + 1], fb = fresnel[3 * n + 2];
  const float ar = clamp01(albedo[3 * n + 0]) * (1.0f / PI_F);
  const float ag = clamp01(albedo[3 * n + 1]) * (1.0f / PI_F);
  const float ab = clamp01(albedo[3 * n + 2]) * (1.0f / PI_F);

  const float NoV0 = vx * nx + vy * ny + vz * nz;
  const float sgn  = (NoV0 >= 0.0f) ? 1.0f : -1.0f;   // jnp.sign; NoV0==0 has prob ~0
  const float Nfx = nx * sgn, Nfy = ny * sgn, Nfz = nz * sgn;
  const float NoV  = fminf(fmaxf(fabsf(NoV0), 1e-6f), 1.0f);
  const float nom1 = NoV * onemk + kk;

  // 12 accumulators: {rgb, wo_indir, wo_vis, indir} x {r,g,b}
  float s0r = 0, s0g = 0, s0b = 0;
  float s1r = 0, s1g = 0, s1b = 0;
  float s2r = 0, s2g = 0, s2b = 0;
  float s3r = 0, s3g = 0, s3b = 0;

  const float* visrow = visibility + (size_t)n * L;
  const float* indrow = indirect + (size_t)n * L * 3;

  for (int i = lane; i < L; i += 64) {
    const float4 ld = s_ld[i];
    const float4 ev = s_env[i];
    const float visv = visrow[i];
    const float ir = indrow[3 * i + 0];
    const float ig = indrow[3 * i + 1];
    const float ib = indrow[3 * i + 2];

    const float cosine = fmaxf(ld.x * nx + ld.y * ny + ld.z * nz, 0.0f);
    const bool  mask   = cosine > 1e-6f;
    const float w      = cosine * ld.w;

    // H = normalize((L+V)/2)
    float hx = 0.5f * (ld.x + vx), hy = 0.5f * (ld.y + vy), hz = 0.5f * (ld.z + vz);
    float hlen = sqrtf(hx * hx + hy * hy + hz * hz);
    float hinv = fast_rcp(fmaxf(hlen, 1e-6f));
    const float Hx = hx * hinv, Hy = hy * hinv, Hz = hz * hinv;

    const float NoL = fminf(fmaxf(Nfx * ld.x + Nfy * ld.y + Nfz * ld.z, 1e-6f), 1.0f);
    const float NoH = fminf(fmaxf(Nfx * Hx + Nfy * Hy + Nfz * Hz, 1e-6f), 1.0f);
    const float VoH = fminf(fmaxf(vx * Hx + vy * Hy + vz * Hz, 1e-6f), 1.0f);

    const float FMi = (-5.55473f * VoH - 6.98316f) * VoH;
    const float p2  = fast_exp2(FMi);
    const float nom0 = NoH * NoH * (alpha2 - 1.0f) + 1.0f;
    const float nom2 = NoL * onemk + kk;
    const float nom  = fminf(fmaxf(FOURPI_F * nom0 * nom0 * nom1 * nom2, 1e-6f), FOURPI_F);
    const float ss   = alpha2 * fast_rcp(nom);

    const float br = ar + (fr + (1.0f - fr) * p2) * ss;
    const float bg = ag + (fg + (1.0f - fg) * p2) * ss;
    const float bb = ab + (fb + (1.0f - fb) * p2) * ss;

    const float vism = mask ? visv : 0.0f;
    const float irm  = mask ? ir : 0.0f;
    const float igm  = mask ? ig : 0.0f;
    const float ibm  = mask ? ib : 0.0f;

    const float vdr = vism * ev.x, vdg = vism * ev.y, vdb = vism * ev.z;
    const float twr = br * w, twg = bg * w, twb = bb * w;

    s0r += twr * (vdr + irm);  s0g += twg * (vdg + igm);  s0b += twb * (vdb + ibm);
    s1r += twr * vdr;          s1g += twg * vdg;          s1b += twb * vdb;
    s2r += twr * ev.x;         s2g += twg * ev.y;         s2b += twb * ev.z;
    s3r += twr * irm;          s3g += twg * igm;          s3b += twb * ibm;
  }

  // Butterfly reduce each accumulator across the 64-lane wave.
#define WAVE_RED(v)                 \
  do {                              \
    v += __shfl_xor(v, 32);         \
    v += __shfl_xor(v, 16);         \
    v += __shfl_xor(v, 8);          \
    v += __shfl_xor(v, 4);          \
    v += __shfl_xor(v, 2);          \
    v += __shfl_xor(v, 1);          \
  } while (0)
  WAVE_RED(s0r); WAVE_RED(s0g); WAVE_RED(s0b);
  WAVE_RED(s1r); WAVE_RED(s1g); WAVE_RED(s1b);
  WAVE_RED(s2r); WAVE_RED(s2g); WAVE_RED(s2b);
  WAVE_RED(s3r); WAVE_RED(s3g); WAVE_RED(s3b);
#undef WAVE_RED

  if (lane == 0) {
    const size_t stride = (size_t)3 * N;
    float* o0 = out + 3 * (size_t)n;             // rgb (clipped to [0,1])
    float* o1 = o0 + stride;                     // wo_indir
    float* o2 = o1 + stride;                     // wo_vis
    float* o3 = o2 + stride;                     // indir
    o0[0] = lin2srgb(clamp01(s0r)); o0[1] = lin2srgb(clamp01(s0g)); o0[2] = lin2srgb(clamp01(s0b));
    o1[0] = lin2srgb(s1r);          o1[1] = lin2srgb(s1g);          o1[2] = lin2srgb(s1b);
    o2[0] = lin2srgb(s2r);          o2[1] = lin2srgb(s2g);          o2[2] = lin2srgb(s2b);
    o3[0] = lin2srgb(s3r);          o3[1] = lin2srgb(s3g);          o3[2] = lin2srgb(s3b);
  }
}

extern "C" void kernel_launch(void* const* d_in, const int* in_sizes, int n_in,
                              void* d_out, int out_size, void* d_ws, size_t ws_size,
                              hipStream_t stream) {
  const float* viewdirs   = (const float*)d_in[0];
  const float* albedo     = (const float*)d_in[1];
  const float* roughness  = (const float*)d_in[2];
  const float* fresnel    = (const float*)d_in[3];
  const float* normal     = (const float*)d_in[4];
  const float* light_dirs = (const float*)d_in[5];
  const float* law        = (const float*)d_in[6];
  const float* env_rgbs   = (const float*)d_in[7];
  const float* visibility = (const float*)d_in[8];
  const float* indirect   = (const float*)d_in[9];
  float* out = (float*)d_out;

  const int N = in_sizes[0] / 3;
  const int L = in_sizes[6];   // light_area_weight is (L,)

  dim3 block(256);
  dim3 grid((N + 3) / 4);  // 4 points (waves) per block
  hipLaunchKernelGGL(tensoir_render, grid, block, 0, stream,
                     viewdirs, albedo, roughness, fresnel, normal,
                     light_dirs, law, env_rgbs, visibility, indirect,
                     out, N, L);
}

// Round 2
// 54.714 us; speedup vs baseline: 1.2071x; 1.2071x over previous
//
#include <hip/hip_runtime.h>
#include <math.h>

// TensoIR physical rendering: N points x L lights -> 4 (N,3) outputs
// (rgb, wo_indir, wo_vis, indir), each linear->sRGB'd after the light sum.
//
// R2 changes vs R1:
//  - rgb = wo_indir + indir (exact algebra) -> 9 accumulators instead of 12
//  - H-normalization via v_rsq on |L+V|^2 (skip /2, skip sqrt+rcp), dot-then-scale
//  - L==512 compile-time specialization, #pragma unroll 4 on the 8-iter light loop
//    so global loads batch up (ILP latency hiding, loop was runtime-trip before)

#define PI_F     3.14159265358979323846f
#define FOURPI_F (4.0f * PI_F)
#define MAXL     512

__device__ __forceinline__ float fast_rcp(float x)  { float r; asm("v_rcp_f32 %0, %1" : "=v"(r) : "v"(x)); return r; }
__device__ __forceinline__ float fast_rsq(float x)  { float r; asm("v_rsq_f32 %0, %1" : "=v"(r) : "v"(x)); return r; }
__device__ __forceinline__ float fast_exp2(float x) { float r; asm("v_exp_f32 %0, %1" : "=v"(r) : "v"(x)); return r; }
__device__ __forceinline__ float fast_log2(float x) { float r; asm("v_log_f32 %0, %1" : "=v"(r) : "v"(x)); return r; }

__device__ __forceinline__ float lin2srgb(float x) {
  float lin = 12.92f * x;
  float xe  = fmaxf(x, 1e-8f);
  float e   = 1.055f * fast_exp2(fast_log2(xe) * (1.0f / 2.4f)) - 0.055f;
  return (x <= 0.0031308f) ? lin : e;
}

__device__ __forceinline__ float clamp01(float x) { return fminf(fmaxf(x, 0.0f), 1.0f); }
__device__ __forceinline__ float clampe(float x)  { return fminf(fmaxf(x, 1e-6f), 1.0f); }

// LC = compile-time light count (0 => runtime L)
template <int LC>
__global__ void __launch_bounds__(256)
tensoir_render(const float* __restrict__ viewdirs,  // (N,3)
               const float* __restrict__ albedo,    // (N,3)
               const float* __restrict__ roughness, // (N,1)
               const float* __restrict__ fresnel,   // (N,3)
               const float* __restrict__ normal,    // (N,3)
               const float* __restrict__ light_dirs,// (L,3)
               const float* __restrict__ law,       // (L,)
               const float* __restrict__ env_rgbs,  // (L,3)
               const float* __restrict__ visibility,// (N,L,1)
               const float* __restrict__ indirect,  // (N,L,3)
               float* __restrict__ out,             // 4*N*3
               int N, int Lrt) {
  __shared__ float4 s_ld[MAXL];   // normalized light dir xyz, area weight
  __shared__ float4 s_env[MAXL];  // env rgb, pad

  const int L = LC ? LC : Lrt;
  const int tid = threadIdx.x;

  for (int l = tid; l < L && l < MAXL; l += 256) {
    float lx = light_dirs[3 * l + 0];
    float ly = light_dirs[3 * l + 1];
    float lz = light_dirs[3 * l + 2];
    float inv = fast_rsq(fmaxf(lx * lx + ly * ly + lz * lz, 1e-12f));
    s_ld[l]  = make_float4(lx * inv, ly * inv, lz * inv, law[l]);
    s_env[l] = make_float4(env_rgbs[3 * l + 0], env_rgbs[3 * l + 1],
                           env_rgbs[3 * l + 2], 0.0f);
  }
  __syncthreads();

  const int lane = tid & 63;
  const int n = blockIdx.x * 4 + (tid >> 6);
  if (n >= N) return;

  // ---- per-point (wave-uniform) setup ----
  float vx = -viewdirs[3 * n + 0], vy = -viewdirs[3 * n + 1], vz = -viewdirs[3 * n + 2];
  {
    float inv = fast_rsq(fmaxf(vx * vx + vy * vy + vz * vz, 1e-12f));
    vx *= inv; vy *= inv; vz *= inv;
  }
  float nx = normal[3 * n + 0], ny = normal[3 * n + 1], nz = normal[3 * n + 2];
  {
    float inv = fast_rsq(fmaxf(nx * nx + ny * ny + nz * nz, 1e-12f));
    nx *= inv; ny *= inv; nz *= inv;
  }
  float rough = roughness[n];
  rough = clamp01(rough * 0.9f + 0.09f);
  const float alpha  = rough * rough;
  const float alpha2 = alpha * alpha;
  const float kk     = (alpha + 2.0f * rough + 1.0f) * 0.125f;
  const float onemk  = 1.0f - kk;

  const float fr = fresnel[3 * n + 0], fg = fresnel[3 * n + 1], fb = fresnel[3 * n + 2];
  const float omfr = 1.0f - fr, omfg = 1.0f - fg, omfb = 1.0f - fb;
  const float ar = clamp01(albedo[3 * n + 0]) * (1.0f / PI_F);
  const float ag = clamp01(albedo[3 * n + 1]) * (1.0f / PI_F);
  const float ab = clamp01(albedo[3 * n + 2]) * (1.0f / PI_F);

  const float NoV0 = vx * nx + vy * ny + vz * nz;
  const float sgn  = (NoV0 >= 0.0f) ? 1.0f : -1.0f;
  const float Nfx = nx * sgn, Nfy = ny * sgn, Nfz = nz * sgn;
  const float NoV  = clampe(fabsf(NoV0));
  const float nom1 = NoV * onemk + kk;

  // 9 accumulators: {wo_indir, wo_vis, indir} x {r,g,b}; rgb = wo_indir+indir.
  float s1r = 0, s1g = 0, s1b = 0;
  float s2r = 0, s2g = 0, s2b = 0;
  float s3r = 0, s3g = 0, s3b = 0;

  const float* visrow = visibility + (size_t)n * L;
  const float* indrow = indirect + (size_t)n * L * 3;

  auto body = [&](int i) {
    const float4 ld = s_ld[i];
    const float4 ev = s_env[i];
    const float visv = visrow[i];
    const float ir = indrow[3 * i + 0];
    const float ig = indrow[3 * i + 1];
    const float ib = indrow[3 * i + 2];

    const float cosine = fmaxf(ld.x * nx + ld.y * ny + ld.z * nz, 0.0f);
    const bool  mask   = cosine > 1e-6f;
    const float w      = cosine * ld.w;

    // h = L+V (direction of H; scale folded into hinv)
    const float hx = ld.x + vx, hy = ld.y + vy, hz = ld.z + vz;
    const float hinv = fast_rsq(fmaxf(hx * hx + hy * hy + hz * hz, 1e-12f));

    const float NoL = clampe(Nfx * ld.x + Nfy * ld.y + Nfz * ld.z);
    const float NoH = clampe((Nfx * hx + Nfy * hy + Nfz * hz) * hinv);
    const float VoH = clampe((vx * hx + vy * hy + vz * hz) * hinv);

    const float FMi = (-5.55473f * VoH - 6.98316f) * VoH;
    const float p2  = fast_exp2(FMi);
    const float nom0 = NoH * NoH * (alpha2 - 1.0f) + 1.0f;
    const float nom2 = NoL * onemk + kk;
    const float nom  = fminf(fmaxf(FOURPI_F * nom0 * nom0 * nom1 * nom2, 1e-6f), FOURPI_F);
    const float ss   = alpha2 * fast_rcp(nom);

    const float br = ar + (fr + omfr * p2) * ss;
    const float bg = ag + (fg + omfg * p2) * ss;
    const float bb = ab + (fb + omfb * p2) * ss;

    const float vism = mask ? visv : 0.0f;
    const float irm  = mask ? ir : 0.0f;
    const float igm  = mask ? ig : 0.0f;
    const float ibm  = mask ? ib : 0.0f;

    const float twr = br * w, twg = bg * w, twb = bb * w;

    s1r += twr * (vism * ev.x);  s1g += twg * (vism * ev.y);  s1b += twb * (vism * ev.z);
    s2r += twr * ev.x;           s2g += twg * ev.y;           s2b += twb * ev.z;
    s3r += twr * irm;            s3g += twg * igm;            s3b += twb * ibm;
  };

  if (LC) {
    constexpr int NITER = LC ? LC / 64 : 1;
#pragma unroll 4
    for (int j = 0; j < NITER; ++j) body(lane + 64 * j);
  } else {
    for (int i = lane; i < L; i += 64) body(i);
  }

#define WAVE_RED(v)                 \
  do {                              \
    v += __shfl_xor(v, 32);         \
    v += __shfl_xor(v, 16);         \
    v += __shfl_xor(v, 8);          \
    v += __shfl_xor(v, 4);          \
    v += __shfl_xor(v, 2);          \
    v += __shfl_xor(v, 1);          \
  } while (0)
  WAVE_RED(s1r); WAVE_RED(s1g); WAVE_RED(s1b);
  WAVE_RED(s2r); WAVE_RED(s2g); WAVE_RED(s2b);
  WAVE_RED(s3r); WAVE_RED(s3g); WAVE_RED(s3b);
#undef WAVE_RED

  if (lane == 0) {
    const size_t stride = (size_t)3 * N;
    float* o0 = out + 3 * (size_t)n;             // rgb
    float* o1 = o0 + stride;                     // wo_indir
    float* o2 = o1 + stride;                     // wo_vis
    float* o3 = o2 + stride;                     // indir
    o0[0] = lin2srgb(clamp01(s1r + s3r));
    o0[1] = lin2srgb(clamp01(s1g + s3g));
    o0[2] = lin2srgb(clamp01(s1b + s3b));
    o1[0] = lin2srgb(s1r); o1[1] = lin2srgb(s1g); o1[2] = lin2srgb(s1b);
    o2[0] = lin2srgb(s2r); o2[1] = lin2srgb(s2g); o2[2] = lin2srgb(s2b);
    o3[0] = lin2srgb(s3r); o3[1] = lin2srgb(s3g); o3[2] = lin2srgb(s3b);
  }
}

extern "C" void kernel_launch(void* const* d_in, const int* in_sizes, int n_in,
                              void* d_out, int out_size, void* d_ws, size_t ws_size,
                              hipStream_t stream) {
  const float* viewdirs   = (const float*)d_in[0];
  const float* albedo     = (const float*)d_in[1];
  const float* roughness  = (const float*)d_in[2];
  const float* fresnel    = (const float*)d_in[3];
  const float* normal     = (const float*)d_in[4];
  const float* light_dirs = (const float*)d_in[5];
  const float* law        = (const float*)d_in[6];
  const float* env_rgbs   = (const float*)d_in[7];
  const float* visibility = (const float*)d_in[8];
  const float* indirect   = (const float*)d_in[9];
  float* out = (float*)d_out;

  const int N = in_sizes[0] / 3;
  const int L = in_sizes[6];   // light_area_weight is (L,)

  dim3 block(256);
  dim3 grid((N + 3) / 4);  // 4 points (waves) per block

  if (L == 512) {
    hipLaunchKernelGGL(tensoir_render<512>, grid, block, 0, stream,
                       viewdirs, albedo, roughness, fresnel, normal,
                       light_dirs, law, env_rgbs, visibility, indirect,
                       out, N, L);
  } else {
    hipLaunchKernelGGL(tensoir_render<0>, grid, block, 0, stream,
                       viewdirs, albedo, roughness, fresnel, normal,
                       light_dirs, law, env_rgbs, visibility, indirect,
                       out, N, L);
  }
}